// Round 13
// baseline (623.225 us; speedup 1.0000x reference)
//
#include <hip/hip_runtime.h>
#include <hip/hip_bf16.h>
#include <math.h>

// Problem constants
#define N_DEST 16000   // B * D_CNT
#define KN     32      // neighbors per dest
#define HIDN   128
#define NH     4
#define SRCD   64
#define EDGED  16
#define XD     80
#define XDP    96      // XD padded to 3 K-tiles of 32
#define WPB    4       // waves per block
#define NPW    4       // nodes per wave (2 pairs)

// bf16 weight workspace layout (shorts)
#define WSB_OFF 0        // W_src padded 128 x 96
#define WKV_OFF 12288    // Wqkv rows 128..383 (K then V), 256 x 128
#define WDB_OFF 45056    // W_dest 128 x 64
#define WQB_OFF 53248    // Wqkv rows 0..127 (Q), 128 x 128
#define WOB_OFF 69632    // Wo 128 x 128
#define PREP_TOT 86016

typedef __attribute__((ext_vector_type(8))) short frag8;   // 8 bf16 (4 VGPR)
typedef __attribute__((ext_vector_type(4))) float f32x4;

// tanh-form GELU (|diff vs exact erf-gelu| <= ~2e-3)
__device__ __forceinline__ float gelu_tanh(float x) {
    float t = x * x;
    float m = fmaf(t, -0.07135481627f, -1.5957691216f);
    float e = __expf(x * m);
    return __fdividef(x, 1.0f + e);
}
__device__ __forceinline__ unsigned short f2bf(float f) {
    __hip_bfloat16 h = __float2bfloat16(f);
    union { __hip_bfloat16 h; unsigned short u; } c; c.h = h; return c.u;
}
__device__ __forceinline__ unsigned int pk2bf(float x, float y) {
    __hip_bfloat162 h2 = __float22bfloat162_rn(make_float2(x, y));
    union { __hip_bfloat162 h; unsigned int u; } c; c.h = h2; return c.u;
}
__device__ __forceinline__ float bflo(unsigned int u) {
    union { unsigned int u; float f; } c; c.u = u << 16; return c.f;
}
__device__ __forceinline__ float bfhi(unsigned int u) {
    union { unsigned int u; float f; } c; c.u = u & 0xFFFF0000u; return c.f;
}
// unpack a bf16x8 weight vector ONCE; reuse for all 4 nodes' FMAs
__device__ __forceinline__ void unpack8(uint4 w, float f[8]) {
    f[0] = bflo(w.x); f[1] = bfhi(w.x); f[2] = bflo(w.y); f[3] = bfhi(w.y);
    f[4] = bflo(w.z); f[5] = bfhi(w.z); f[6] = bflo(w.w); f[7] = bfhi(w.w);
}
__device__ __forceinline__ float dotu(const float f[8], float4 x0, float4 x1, float acc) {
    acc = fmaf(f[0], x0.x, acc); acc = fmaf(f[1], x0.y, acc);
    acc = fmaf(f[2], x0.z, acc); acc = fmaf(f[3], x0.w, acc);
    acc = fmaf(f[4], x1.x, acc); acc = fmaf(f[5], x1.y, acc);
    acc = fmaf(f[6], x1.z, acc); acc = fmaf(f[7], x1.w, acc);
    return acc;
}
__device__ __forceinline__ frag8 pack_frag(float4 f0, float4 f1) {
    union { frag8 f; uint4 u; } c;
    c.u.x = pk2bf(f0.x, f0.y); c.u.y = pk2bf(f0.z, f0.w);
    c.u.z = pk2bf(f1.x, f1.y); c.u.w = pk2bf(f1.z, f1.w);
    return c.f;
}
__device__ __forceinline__ frag8 zero_frag() {
    union { frag8 f; uint4 u; } c;
    c.u = make_uint4(0u, 0u, 0u, 0u);
    return c.f;
}

// ---- prep: convert all weight matrices to bf16 in d_ws ----
__global__ void prep_weights(const float* __restrict__ W_src,
                             const float* __restrict__ W_dest,
                             const float* __restrict__ Wqkv,
                             const float* __restrict__ Wo,
                             unsigned short* __restrict__ ws) {
    int i = blockIdx.x * 256 + threadIdx.x;
    if (i < WKV_OFF) {                       // W_src 128 x 96 (pad K 80->96)
        int r = i / XDP, c = i - r * XDP;
        ws[i] = f2bf(c < XD ? W_src[r * XD + c] : 0.0f);
    } else if (i < WDB_OFF) {                // Wqkv K/V rows
        int j = i - WKV_OFF;
        ws[i] = f2bf(Wqkv[128 * HIDN + j]);
    } else if (i < WQB_OFF) {                // W_dest
        ws[i] = f2bf(W_dest[i - WDB_OFF]);
    } else if (i < WOB_OFF) {                // Wqkv Q rows
        ws[i] = f2bf(Wqkv[i - WQB_OFF]);
    } else if (i < PREP_TOT) {               // Wo
        ws[i] = f2bf(Wo[i - WOB_OFF]);
    }
}

// ---- phase C body: GEMM-D for one node -> gelu -> swizzled s_sin slot ----
__device__ __forceinline__ void gemm_d_node(
    int n, int a0, int a1,
    const float* __restrict__ src, const float* __restrict__ edges,
    const float* __restrict__ b_src, const unsigned short* __restrict__ Wsb,
    unsigned short (*sinp)[128], int lg, int lm)
{
    frag8 aall[3][2];
    #pragma unroll
    for (int kt = 0; kt < 2; ++kt) {
        const int c0 = kt * 32 + lg * 8;
        if (a0) {
            const float4* p = (const float4*)(src + (size_t)(a0 - 1) * SRCD + c0);
            aall[kt][0] = pack_frag(p[0], p[1]);
        } else aall[kt][0] = zero_frag();
        if (a1) {
            const float4* p = (const float4*)(src + (size_t)(a1 - 1) * SRCD + c0);
            aall[kt][1] = pack_frag(p[0], p[1]);
        } else aall[kt][1] = zero_frag();
    }
    if (lg < 2) {   // x-cols 64..79 = edges 0..15
        const float4* p0 = (const float4*)(edges + ((size_t)lm * N_DEST + n) * EDGED + lg * 8);
        const float4* p1 = (const float4*)(edges + ((size_t)(lm + 16) * N_DEST + n) * EDGED + lg * 8);
        aall[2][0] = pack_frag(p0[0], p0[1]);
        aall[2][1] = pack_frag(p1[0], p1[1]);
    } else {        // x-cols 80..95 = zero pad
        aall[2][0] = zero_frag(); aall[2][1] = zero_frag();
    }

    #pragma unroll 1
    for (int half = 0; half < 2; ++half) {
        f32x4 acc[2][4];
        #pragma unroll
        for (int ct = 0; ct < 4; ++ct) {
            float bias = b_src[(half * 4 + ct) * 16 + lm];
            acc[0][ct] = (f32x4){bias, bias, bias, bias};
            acc[1][ct] = (f32x4){bias, bias, bias, bias};
        }
        #pragma unroll
        for (int kt = 0; kt < 3; ++kt) {
            #pragma unroll
            for (int ct = 0; ct < 4; ++ct) {
                frag8 b = *(const frag8*)(Wsb + (size_t)((half * 4 + ct) * 16 + lm) * XDP + kt * 32 + lg * 8);
                acc[0][ct] = __builtin_amdgcn_mfma_f32_16x16x32_bf16(aall[kt][0], b, acc[0][ct], 0, 0, 0);
                acc[1][ct] = __builtin_amdgcn_mfma_f32_16x16x32_bf16(aall[kt][1], b, acc[1][ct], 0, 0, 0);
            }
        }
        #pragma unroll
        for (int r = 0; r < 2; ++r)
            #pragma unroll
            for (int ct = 0; ct < 4; ++ct)
                #pragma unroll
                for (int e = 0; e < 4; ++e) {
                    const int row = r * 16 + lg * 4 + e;
                    const int cb  = ((half * 4 + ct) * 16 + lm) * 2;
                    const int byt = (cb ^ ((row & 7) << 4));
                    *(unsigned short*)((char*)&sinp[row][0] + byt) =
                        f2bf(gelu_tanh(acc[r][ct][e]));
                }
    }
}

// ---- softmax for one head, one node; q0/q1 supplied by caller ----
__device__ __forceinline__ void softmax_head(
    const f32x4 (&acc)[2][4], unsigned mw, float q0, float q1,
    float* __restrict__ attn_row, int hp, int lg, int lm)
{
    float vals[8];    // j = r*4+e -> kk = 16r + lg*4 + e
    #pragma unroll
    for (int r = 0; r < 2; ++r)
        #pragma unroll
        for (int e = 0; e < 4; ++e) {
            float v = acc[r][2 * hp][e] * q0 + acc[r][2 * hp + 1][e] * q1;
            v += __shfl_xor(v, 1); v += __shfl_xor(v, 2);
            v += __shfl_xor(v, 4); v += __shfl_xor(v, 8);
            vals[r * 4 + e] = v;
        }
    float m8 = -1e30f;
    #pragma unroll
    for (int j = 0; j < 8; ++j) {
        const int kk = (j >> 2) * 16 + lg * 4 + (j & 3);
        if ((mw >> kk) & 1u) vals[j] = -1e30f;
        m8 = fmaxf(m8, vals[j]);
    }
    m8 = fmaxf(m8, __shfl_xor(m8, 16));
    m8 = fmaxf(m8, __shfl_xor(m8, 32));
    float ex[8], s8 = 0.0f;
    #pragma unroll
    for (int j = 0; j < 8; ++j) { ex[j] = __expf(vals[j] - m8); s8 += ex[j]; }
    s8 += __shfl_xor(s8, 16); s8 += __shfl_xor(s8, 32);
    const float inv = __fdividef(1.0f, s8);
    if (lm == 0) {
        *(float4*)&attn_row[lg * 4] =
            make_float4(ex[0] * inv, ex[1] * inv, ex[2] * inv, ex[3] * inv);
        *(float4*)&attn_row[16 + lg * 4] =
            make_float4(ex[4] * inv, ex[5] * inv, ex[6] * inv, ex[7] * inv);
    }
}

// ---- PV for one node from V-chunk accumulators ----
__device__ __forceinline__ void pv_node(
    const f32x4 (&acc)[2][4], const float (*attn)[KN],
    float* __restrict__ ctx, int ch, int lg, int lm)
{
    const int hb = (ch - 2) * 2;
    float4 at[2][2];    // [hp][r]
    #pragma unroll
    for (int hp = 0; hp < 2; ++hp)
        #pragma unroll
        for (int r = 0; r < 2; ++r)
            at[hp][r] = *(const float4*)&attn[hb + hp][r * 16 + lg * 4];
    #pragma unroll
    for (int ct = 0; ct < 4; ++ct) {
        const int hp = ct >> 1;
        float v = 0.0f;
        #pragma unroll
        for (int r = 0; r < 2; ++r) {
            v = fmaf(at[hp][r].x, acc[r][ct][0], v);
            v = fmaf(at[hp][r].y, acc[r][ct][1], v);
            v = fmaf(at[hp][r].z, acc[r][ct][2], v);
            v = fmaf(at[hp][r].w, acc[r][ct][3], v);
        }
        v += __shfl_xor(v, 16); v += __shfl_xor(v, 32);
        if (lg == 0) ctx[(ch - 2) * 64 + ct * 16 + lm] = v;
    }
}

// ---- phases C+D for one PAIR of nodes (s_sin slots reused per pair) ----
__device__ __forceinline__ void process_pair(
    int na, int nb, int a0a, int a1a, int a0b, int a1b,
    unsigned mwa, unsigned mwb,
    float qla, float qha, float qlb, float qhb,   // q[lane], q[lane+64] per node
    const float* __restrict__ src, const float* __restrict__ edges,
    const float* __restrict__ b_src, const float* __restrict__ bqkv,
    const unsigned short* __restrict__ Wsb, const unsigned short* __restrict__ Wkv,
    unsigned short (*sinA)[128], unsigned short (*sinB)[128],
    float* __restrict__ dcA, float* __restrict__ dcB,
    float (*attnA)[KN], float (*attnB)[KN],
    int lg, int lm)
{
    gemm_d_node(na, a0a, a1a, src, edges, b_src, Wsb, sinA, lg, lm);
    gemm_d_node(nb, a0b, a1b, src, edges, b_src, Wsb, sinB, lg, lm);
    __builtin_amdgcn_wave_barrier();

    #pragma unroll 1
    for (int ch = 0; ch < 4; ++ch) {
        f32x4 ac0[2][4], ac1[2][4];
        #pragma unroll
        for (int ct = 0; ct < 4; ++ct) {
            float bias = bqkv[128 + ch * 64 + ct * 16 + lm];
            ac0[0][ct] = (f32x4){bias, bias, bias, bias};
            ac0[1][ct] = ac0[0][ct];
            ac1[0][ct] = ac0[0][ct];
            ac1[1][ct] = ac0[0][ct];
        }
        #pragma unroll
        for (int kt = 0; kt < 4; ++kt) {
            const int off = (kt * 64 + lg * 16) ^ ((lm & 7) << 4);
            frag8 a00f = *(const frag8*)((const char*)&sinA[lm][0] + off);
            frag8 a01f = *(const frag8*)((const char*)&sinA[16 + lm][0] + off);
            frag8 a10f = *(const frag8*)((const char*)&sinB[lm][0] + off);
            frag8 a11f = *(const frag8*)((const char*)&sinB[16 + lm][0] + off);
            #pragma unroll
            for (int ct = 0; ct < 4; ++ct) {
                frag8 b = *(const frag8*)(Wkv + (size_t)(ch * 64 + ct * 16 + lm) * HIDN + kt * 32 + lg * 8);
                ac0[0][ct] = __builtin_amdgcn_mfma_f32_16x16x32_bf16(a00f, b, ac0[0][ct], 0, 0, 0);
                ac0[1][ct] = __builtin_amdgcn_mfma_f32_16x16x32_bf16(a01f, b, ac0[1][ct], 0, 0, 0);
                ac1[0][ct] = __builtin_amdgcn_mfma_f32_16x16x32_bf16(a10f, b, ac1[0][ct], 0, 0, 0);
                ac1[1][ct] = __builtin_amdgcn_mfma_f32_16x16x32_bf16(a11f, b, ac1[1][ct], 0, 0, 0);
            }
        }
        if (ch < 2) {
            #pragma unroll
            for (int hp = 0; hp < 2; ++hp) {
                const int head = ch * 2 + hp;
                float qsa = (ch == 0) ? qla : qha;
                float qsb = (ch == 0) ? qlb : qhb;
                float qa0 = __shfl(qsa, hp * 32 + lm);
                float qa1 = __shfl(qsa, hp * 32 + 16 + lm);
                float qb0 = __shfl(qsb, hp * 32 + lm);
                float qb1 = __shfl(qsb, hp * 32 + 16 + lm);
                softmax_head(ac0, mwa, qa0, qa1, attnA[head], hp, lg, lm);
                softmax_head(ac1, mwb, qb0, qb1, attnB[head], hp, lg, lm);
            }
        } else {
            pv_node(ac0, attnA, dcA, ch, lg, lm);
            pv_node(ac1, attnB, dcB, ch, lg, lm);
        }
    }
    __builtin_amdgcn_wave_barrier();
}

__global__ __launch_bounds__(256, 2) void fused_gat_wave(
    const float* __restrict__ src,    // (16000, 64)
    const float* __restrict__ dest,   // (16000, 64)
    const int*   __restrict__ adj,    // (32, 16000)
    const int*   __restrict__ mask,   // (16000, 32)
    const float* __restrict__ edges,  // (32, 16000, 16)
    const float* __restrict__ b_src,
    const float* __restrict__ b_dest,
    const float* __restrict__ bqkv,
    const float* __restrict__ bo,
    const float* __restrict__ ln_g,
    const float* __restrict__ ln_b,
    const unsigned short* __restrict__ ws,   // bf16 weights
    float* __restrict__ out)
{
    const int tid  = threadIdx.x;
    const int wv   = tid >> 6;        // wave id 0..3
    const int lane = tid & 63;
    const int lg   = lane >> 4;       // 0..3
    const int lm   = lane & 15;       // 0..15
    const int n0   = (blockIdx.x * WPB + wv) * NPW;   // nodes n0..n0+3

    const unsigned short* Wsb = ws + WSB_OFF;
    const unsigned short* Wkv = ws + WKV_OFF;
    const unsigned short* Wdb = ws + WDB_OFF;
    const unsigned short* Wqb = ws + WQB_OFF;
    const unsigned short* Wob = ws + WOB_OFF;

    // per-wave LDS slices; zero __syncthreads.
    // s_sin: 2 slots reused per pair. total = 65536 + 8192 + 4096 = 77824 B -> 2 blocks/CU.
    __shared__ __align__(16) unsigned short s_sin[WPB][2][KN][128];   // 65536 B
    __shared__ __align__(16) float s_dc[WPB][NPW][HIDN];              // 8192 B (dest_in, then ctx)
    __shared__ __align__(16) float s_attn[WPB][2][NH][KN];            // 4096 B (pair-local)

    // ---- hoisted per-lane loads ----
    int a0[NPW], a1[NPW];
    #pragma unroll
    for (int nd = 0; nd < NPW; ++nd) {
        a0[nd] = adj[lm * N_DEST + n0 + nd];
        a1[nd] = adj[(lm + 16) * N_DEST + n0 + nd];
    }
    const int mvA = mask[n0 * KN + lane];          // nodes n0 (lanes 0-31), n0+1 (32-63)
    const int mvB = mask[(n0 + 2) * KN + lane];    // nodes n0+2, n0+3
    const unsigned long long balA = __ballot(mvA != 0);
    const unsigned long long balB = __ballot(mvB != 0);
    const unsigned mw0 = (unsigned)balA, mw1 = (unsigned)(balA >> 32);
    const unsigned mw2 = (unsigned)balB, mw3 = (unsigned)(balB >> 32);

    // ---------------- phase A: dest_in (gelu) for 4 nodes ----------------
    {
        float da[NPW][2];
        float bd0 = b_dest[lane], bd1 = b_dest[lane + 64];
        #pragma unroll
        for (int nd = 0; nd < NPW; ++nd) { da[nd][0] = bd0; da[nd][1] = bd1; }
        const unsigned short* w0p = Wdb + (size_t)lane * SRCD;
        const unsigned short* w1p = Wdb + (size_t)(lane + 64) * SRCD;
        #pragma unroll
        for (int c = 0; c < 8; ++c) {
            float wf0[8], wf1[8];
            unpack8(*(const uint4*)(w0p + c * 8), wf0);
            unpack8(*(const uint4*)(w1p + c * 8), wf1);
            #pragma unroll
            for (int nd = 0; nd < NPW; ++nd) {
                const float* dr = dest + (size_t)(n0 + nd) * SRCD + c * 8;
                float4 x0 = *(const float4*)dr;
                float4 x1 = *(const float4*)(dr + 4);
                da[nd][0] = dotu(wf0, x0, x1, da[nd][0]);
                da[nd][1] = dotu(wf1, x0, x1, da[nd][1]);
            }
        }
        #pragma unroll
        for (int nd = 0; nd < NPW; ++nd) {
            s_dc[wv][nd][lane]      = gelu_tanh(da[nd][0]);
            s_dc[wv][nd][lane + 64] = gelu_tanh(da[nd][1]);
        }
    }
    __builtin_amdgcn_wave_barrier();

    // ---------------- phase B: q projection for 4 nodes -> registers ----------
    float q_l[NPW], q_h[NPW];
    {
        float qa[NPW][2];
        float bq0 = bqkv[lane], bq1 = bqkv[lane + 64];
        #pragma unroll
        for (int nd = 0; nd < NPW; ++nd) { qa[nd][0] = bq0; qa[nd][1] = bq1; }
        const unsigned short* w0p = Wqb + (size_t)lane * HIDN;
        const unsigned short* w1p = Wqb + (size_t)(lane + 64) * HIDN;
        #pragma unroll
        for (int c = 0; c < 16; ++c) {
            float wf0[8], wf1[8];
            unpack8(*(const uint4*)(w0p + c * 8), wf0);
            unpack8(*(const uint4*)(w1p + c * 8), wf1);
            #pragma unroll
            for (int nd = 0; nd < NPW; ++nd) {
                float4 x0 = *(const float4*)&s_dc[wv][nd][c * 8];
                float4 x1 = *(const float4*)&s_dc[wv][nd][c * 8 + 4];
                qa[nd][0] = dotu(wf0, x0, x1, qa[nd][0]);
                qa[nd][1] = dotu(wf1, x0, x1, qa[nd][1]);
            }
        }
        const float sc = 0.17677669529663688110f;   // 1/sqrt(32)
        #pragma unroll
        for (int nd = 0; nd < NPW; ++nd) {
            q_l[nd] = qa[nd][0] * sc;
            q_h[nd] = qa[nd][1] * sc;
        }
    }
    __builtin_amdgcn_wave_barrier();

    // ---------------- phases C+D per pair (s_sin slots reused) ----------------
    process_pair(n0,     n0 + 1, a0[0], a1[0], a0[1], a1[1], mw0, mw1,
                 q_l[0], q_h[0], q_l[1], q_h[1],
                 src, edges, b_src, bqkv, Wsb, Wkv,
                 s_sin[wv][0], s_sin[wv][1], s_dc[wv][0], s_dc[wv][1],
                 s_attn[wv][0], s_attn[wv][1], lg, lm);
    process_pair(n0 + 2, n0 + 3, a0[2], a1[2], a0[3], a1[3], mw2, mw3,
                 q_l[2], q_h[2], q_l[3], q_h[3],
                 src, edges, b_src, bqkv, Wsb, Wkv,
                 s_sin[wv][0], s_sin[wv][1], s_dc[wv][2], s_dc[wv][3],
                 s_attn[wv][0], s_attn[wv][1], lg, lm);

    // ---------------- phase E: out projection, x2, layernorm, 4 nodes ---------
    {
        float oa[NPW][2];
        float bo0 = bo[lane], bo1 = bo[lane + 64];
        #pragma unroll
        for (int nd = 0; nd < NPW; ++nd) { oa[nd][0] = bo0; oa[nd][1] = bo1; }
        const unsigned short* w0p = Wob + (size_t)lane * HIDN;
        const unsigned short* w1p = Wob + (size_t)(lane + 64) * HIDN;
        #pragma unroll
        for (int c = 0; c < 16; ++c) {
            float wf0[8], wf1[8];
            unpack8(*(const uint4*)(w0p + c * 8), wf0);
            unpack8(*(const uint4*)(w1p + c * 8), wf1);
            #pragma unroll
            for (int nd = 0; nd < NPW; ++nd) {
                float4 x0 = *(const float4*)&s_dc[wv][nd][c * 8];
                float4 x1 = *(const float4*)&s_dc[wv][nd][c * 8 + 4];
                oa[nd][0] = dotu(wf0, x0, x1, oa[nd][0]);
                oa[nd][1] = dotu(wf1, x0, x1, oa[nd][1]);
            }
        }
        float g0 = ln_g[lane], g1 = ln_g[lane + 64];
        float t0 = ln_b[lane], t1 = ln_b[lane + 64];
        #pragma unroll
        for (int nd = 0; nd < NPW; ++nd) {
            float o0 = oa[nd][0] * 2.0f, o1 = oa[nd][1] * 2.0f;
            float s = o0 + o1, ss = o0 * o0 + o1 * o1;
            #pragma unroll
            for (int off = 1; off < 64; off <<= 1) {
                s  += __shfl_xor(s, off);
                ss += __shfl_xor(ss, off);
            }
            float mu  = s * (1.0f / HIDN);
            float var = ss * (1.0f / HIDN) - mu * mu;
            float rs  = rsqrtf(var + 1e-5f);
            out[(size_t)(n0 + nd) * HIDN + lane]      = (o0 - mu) * rs * g0 + t0;
            out[(size_t)(n0 + nd) * HIDN + lane + 64] = (o1 - mu) * rs * g1 + t1;
        }
    }
}

extern "C" void kernel_launch(void* const* d_in, const int* in_sizes, int n_in,
                              void* d_out, int out_size, void* d_ws, size_t ws_size,
                              hipStream_t stream) {
    const float* src    = (const float*)d_in[0];
    const float* dest   = (const float*)d_in[1];
    const int*   adj    = (const int*)  d_in[2];
    const int*   mask   = (const int*)  d_in[3];
    const float* edges  = (const float*)d_in[4];
    const float* W_src  = (const float*)d_in[5];
    const float* b_src  = (const float*)d_in[6];
    const float* W_dest = (const float*)d_in[7];
    const float* b_dest = (const float*)d_in[8];
    const float* Wqkv   = (const float*)d_in[9];
    const float* bqkv   = (const float*)d_in[10];
    const float* Wo     = (const float*)d_in[11];
    const float* bo     = (const float*)d_in[12];
    const float* ln_g   = (const float*)d_in[13];
    const float* ln_b   = (const float*)d_in[14];
    float* outp = (float*)d_out;

    unsigned short* ws = (unsigned short*)d_ws;
    prep_weights<<<PREP_TOT / 256, 256, 0, stream>>>(W_src, W_dest, Wqkv, Wo, ws);

    fused_gat_wave<<<N_DEST / (WPB * NPW), 256, 0, stream>>>(
        src, dest, adj, mask, edges, b_src, b_dest, bqkv, bo, ln_g, ln_b,
        ws, outp);
}